// Round 6
// baseline (969.687 us; speedup 1.0000x reference)
//
#include <hip/hip_runtime.h>
#include <cstdint>
#include <cstddef>

// RobustGCN forward on MI355X.
//   1. graph prep v2 — global-atomic build (r6): zero -> countA (fire-and-forget
//      atomicAdd on L2-resident cnt) -> scan1(+dd)/scan2/scan3(+cursor) ->
//      scatterA (returning atomic cursor, csr scatter). Replaces the 7-kernel
//      bucket sort (~130MB streamed) with ~38MB + 4 fewer launches.
//   2. GEMM1 (r2-proven gemm1f, 177us): BM=BN=128, BK=32, 4 waves, dbuf 48KB LDS,
//      A f32 + B f16 via global_load_lds width-16 (linear dest, inv-swizzled src),
//      cvt at frag build. 3 blocks/CU cross-block overlap hides the vmcnt drain.
//      (r5 lesson: reg-staged A + ds_write = 226us — gload_lds wins. r4 lesson:
//      separate cvtx pass costs more than it saves.)
//   3. GEMM2 (f16 MFMA, reg-dbuf, block-diag W) + fused attention epilogue ->
//      Mcat[r][c] = pack_h2(dis_r*m*exp(-v), di_r*v*exp(-2v))  (deg weights FOLDED)
//   4. fused dual SpMM (CSR, wave/node, lane/class, 8-edge batches = 8 gathers
//      in flight) — no dd gather (folded) + sample*sqrt(var) + log_softmax

typedef _Float16 h8 __attribute__((ext_vector_type(8)));
typedef _Float16 h2 __attribute__((ext_vector_type(2)));
typedef float f32x4 __attribute__((ext_vector_type(4)));
typedef unsigned int uint32;

static __device__ __forceinline__ float elu_f(float z) {
  return z > 0.f ? z : expm1f(z);
}

// async global->LDS, 16B per lane. Dest must be wave-linear (base + lane*16).
static __device__ __forceinline__ void gload16(const void* g, void* l) {
  __builtin_amdgcn_global_load_lds(
      (__attribute__((address_space(1))) void*)g,
      (__attribute__((address_space(3))) void*)l, 16, 0, 0);
}

// ---------------- graph prep: atomic CSR build ----------------
__global__ __launch_bounds__(256) void zero_k(int* __restrict__ cnt, int n) {
  int idx = blockIdx.x * 256 + threadIdx.x;
  if (idx < n) cnt[idx] = 0;
}

__global__ __launch_bounds__(256) void countA_k(const int* __restrict__ esrc, int E,
                                                int* __restrict__ cnt) {
  int idx = blockIdx.x * 256 + threadIdx.x;
  if (idx < E) atomicAdd(&cnt[esrc[idx]], 1);   // no return -> fire-and-forget
}

__global__ __launch_bounds__(256) void scatterA_k(
    const int* __restrict__ esrc, const int* __restrict__ edst, int E,
    int* __restrict__ cur, int* __restrict__ csr) {
  int idx = blockIdx.x * 256 + threadIdx.x;
  if (idx < E) {
    int s = esrc[idx];
    int pos = atomicAdd(&cur[s], 1);
    csr[pos] = edst[idx];
  }
}

// ---------------- padded row-start scan ----------------
// exclusive scan of PADDED counts ((cnt+3)&~3) so every CSR row start is 16B-aligned
// scan1 also emits the degree weights dd = (rsqrt(deg+1), 1/(deg+1)).
__global__ void scan1_k(const int* __restrict__ cnt, int* __restrict__ excl,
                        int* __restrict__ bsum, float2* __restrict__ dd, int n) {
  __shared__ int sh[256];
  int t = threadIdx.x, idx = blockIdx.x * 256 + t;
  int c = (idx < n) ? cnt[idx] : 0;
  if (idx < n) {
    float d = (float)(c + 1);
    dd[idx] = make_float2(rsqrtf(d), 1.f / d);
  }
  int v = (c + 3) & ~3;
  sh[t] = v;
  __syncthreads();
  for (int off = 1; off < 256; off <<= 1) {
    int add = (t >= off) ? sh[t - off] : 0;
    __syncthreads();
    sh[t] += add;
    __syncthreads();
  }
  if (idx < n) excl[idx] = sh[t] - v;
  if (t == 255) bsum[blockIdx.x] = sh[255];
}

__global__ void scan2_k(const int* __restrict__ bsum, int* __restrict__ boff, int nb) {
  __shared__ int sh[512];
  int t = threadIdx.x;
  int v = (t < nb) ? bsum[t] : 0;
  sh[t] = v;
  __syncthreads();
  for (int off = 1; off < 512; off <<= 1) {
    int add = (t >= off) ? sh[t - off] : 0;
    __syncthreads();
    sh[t] += add;
    __syncthreads();
  }
  if (t < nb) boff[t] = sh[t] - v;
}

// scan3 also initializes the scatter cursors (cur = row_start).
__global__ void scan3_k(int* __restrict__ excl, const int* __restrict__ boff,
                        int* __restrict__ cur, int n) {
  int idx = blockIdx.x * 256 + threadIdx.x;
  if (idx < n) {
    int v = excl[idx] + boff[blockIdx.x];
    excl[idx] = v;
    cur[idx] = v;
  }
}

// ---------------- weight prep: transpose + f16 + fuse ----------------
__global__ void prep_w_k(const float* __restrict__ Wm0, const float* __restrict__ Wv0,
                         const float* __restrict__ Wm1, const float* __restrict__ Wv1,
                         _Float16* __restrict__ W1t, _Float16* __restrict__ W2t) {
  int idx = blockIdx.x * 256 + threadIdx.x;
  if (idx < 512 * 512) {
    int n = idx >> 9, k = idx & 511;
    float v = (n < 256) ? Wm0[k * 256 + n] : Wv0[k * 256 + (n - 256)];
    W1t[idx] = (_Float16)v;
  }
  if (idx < 128 * 512) {
    int n = idx >> 9, k = idx & 511;
    float v = 0.f;
    if (n < 64) { if (k < 256) v = Wm1[k * 64 + n]; }
    else        { if (k >= 256) v = Wv1[(k - 256) * 64 + (n - 64)]; }
    W2t[idx] = (_Float16)v;
  }
}

// ---------------- GEMM1 (r2-proven): Hcat = act(x @ W1t^T + b) ----------------
// BM=128, BN=128, BK=32, K=512 (16 iters). 4 waves (2m x 2n), acc 4x4 frags.
// LDS 48KB: Af32[2][128][32] @ 0/16384 (16B-slot swizzle ^row&7),
//           Bf16[2][128][32] @ 32768/40960 (16B-slot swizzle ^(row>>1)&3).
// global_load_lds width-16, linear LDS dest, inverse-swizzled global source.
// 3 blocks/CU -> cross-block overlap hides per-iter vmcnt(0)+barrier drain.
__global__ __launch_bounds__(256) void gemm1f_k(
    const float* __restrict__ A, const _Float16* __restrict__ Bt,
    const float* __restrict__ b0, const float* __restrict__ b1,
    _Float16* __restrict__ out, int M, int mtiles) {
  __shared__ __align__(16) unsigned char ldsb[49152];

  const int sg = blockIdx.x >> 5, loc = blockIdx.x & 31;
  const int nt = loc >> 3, mtl = loc & 7;
  const int mt = sg * 8 + mtl;
  if (mt >= mtiles) return;
  const int m0 = mt * 128, n0 = nt * 128;
  const int t = threadIdx.x;
  const int lane = t & 63;
  const int wave = t >> 6;
  const int wm = wave >> 1, wn = wave & 1;
  const int lr = lane & 15, quad = lane >> 4;

  const int ra = t >> 3;
  const int asw = ((t & 7) ^ (ra & 7)) << 2;
  const int rb = t >> 2;
  const int bsw = ((t & 3) ^ ((t >> 3) & 3)) << 3;

  f32x4 acc[4][4] = {};

  auto stage = [&](int b, int kt) {
#pragma unroll
    for (int i = 0; i < 4; i++) {
      const float* src = A + (size_t)min(m0 + i * 32 + ra, M - 1) * 512 + kt + asw;
      gload16(src, ldsb + b * 16384 + i * 4096 + t * 16);
    }
#pragma unroll
    for (int i = 0; i < 2; i++) {
      const _Float16* src = Bt + (size_t)(n0 + i * 64 + rb) * 512 + kt + bsw;
      gload16(src, ldsb + 32768 + b * 8192 + i * 4096 + t * 16);
    }
  };

  stage(0, 0);
  __syncthreads();

  int cur = 0;
  const int zA = lr & 7;
  const int zB = (lr >> 1) & 3;
  for (int kt = 0; kt < 512; kt += 32) {
    if (kt + 32 < 512) stage(cur ^ 1, kt + 32);
    const unsigned char* Ab = ldsb + cur * 16384;
    const unsigned char* Bb = ldsb + 32768 + cur * 8192;
    h8 bf[4];
#pragma unroll
    for (int j = 0; j < 4; j++) {
      int row = wn * 64 + j * 16 + lr;
      bf[j] = *(const h8*)(Bb + row * 64 + ((quad ^ zB) << 4));
    }
    h8 af[4];
#pragma unroll
    for (int i = 0; i < 4; i++) {
      int R = wm * 64 + i * 16 + lr;
      const float4 a0 = *(const float4*)(Ab + R * 128 + (((2 * quad) ^ zA) << 4));
      const float4 a1 = *(const float4*)(Ab + R * 128 + (((2 * quad + 1) ^ zA) << 4));
      af[i] = h8{(_Float16)a0.x, (_Float16)a0.y, (_Float16)a0.z, (_Float16)a0.w,
                 (_Float16)a1.x, (_Float16)a1.y, (_Float16)a1.z, (_Float16)a1.w};
    }
#pragma unroll
    for (int i = 0; i < 4; i++)
#pragma unroll
      for (int j = 0; j < 4; j++)
        acc[i][j] = __builtin_amdgcn_mfma_f32_16x16x32_f16(af[i], bf[j], acc[i][j], 0, 0, 0);
    __syncthreads();
    cur ^= 1;
  }

  // epilogue: bias+act in regs -> f16 LDS tile (stride 136) -> 16B coalesced stores
  _Float16* lt = (_Float16*)ldsb;
#pragma unroll
  for (int j = 0; j < 4; j++) {
    int gc = n0 + wn * 64 + j * 16 + lr;
    float bj = (gc < 256) ? b0[gc] : b1[gc - 256];
#pragma unroll
    for (int i = 0; i < 4; i++) {
#pragma unroll
      for (int r = 0; r < 4; r++) {
        float z = acc[i][j][r] + bj;
        float v = (gc < 256) ? elu_f(z) : fmaxf(z, 0.f);
        lt[(wm * 64 + i * 16 + quad * 4 + r) * 136 + wn * 64 + j * 16 + lr] = (_Float16)v;
      }
    }
  }
  __syncthreads();
  {
    const int row = t >> 1, col0 = (t & 1) * 64;
    const int gr = m0 + row;
    if (gr < M) {
      _Float16* dst = out + (size_t)gr * 512 + n0 + col0;
#pragma unroll
      for (int k = 0; k < 8; k++)
        *(h8*)(dst + k * 8) = *(h8*)&lt[row * 136 + col0 + k * 8];
    }
  }
}

// ---------------- GEMM2 + fused attention (reg-dbuf) ----------------
// BM=128, N=128 (cols 0..63 mean, 64..127 var). 4 waves, wave = 32 rows x 8 j-tiles.
// Epilogue folds the dst-side degree weights into Mcat:
//   Mcat[r][c] = pack_h2(dis_r * m*exp(-v), di_r * v*exp(-2v))
// so the SpMM gather needs NO dd[dst] lookup (w0=dis_s*dis_d, w1=di_s*di_d).
__global__ __launch_bounds__(256) void gemm2_k(
    const _Float16* __restrict__ A, const _Float16* __restrict__ Bt,
    const float* __restrict__ bm1, const float* __restrict__ bv1,
    const float2* __restrict__ dd, uint32* __restrict__ Mcat, int M, int K) {
  __shared__ _Float16 lds[20480];
  _Float16* As = lds;
  _Float16* Bs = lds + 10240;
  const int m0 = blockIdx.x * 128;
  const int t = threadIdx.x;
  const int lane = t & 63;
  const int wave = t >> 6;
  const int lr = lane & 15, quad = lane >> 4;
  const int trow = t >> 2;
  const int tkc = (t & 3) * 8;

  const size_t arow0 = (size_t)min(m0 + trow, M - 1) * K;
  const size_t arow1 = (size_t)min(m0 + trow + 64, M - 1) * K;
  const size_t brow0 = (size_t)trow * K;
  const size_t brow1 = (size_t)(trow + 64) * K;

  f32x4 acc[2][8] = {};
  h8 pa[2], pb[2];

  pa[0] = *(const h8*)(A + arow0 + tkc);
  pa[1] = *(const h8*)(A + arow1 + tkc);
  pb[0] = *(const h8*)(Bt + brow0 + tkc);
  pb[1] = *(const h8*)(Bt + brow1 + tkc);
  *(h8*)&As[trow * 40 + tkc] = pa[0];
  *(h8*)&As[(trow + 64) * 40 + tkc] = pa[1];
  *(h8*)&Bs[trow * 40 + tkc] = pb[0];
  *(h8*)&Bs[(trow + 64) * 40 + tkc] = pb[1];
  __syncthreads();

  for (int kt = 0; kt < K; kt += 32) {
    const int cur = (kt >> 5) & 1;
    const int curo = cur * 5120;
    const bool more = (kt + 32) < K;
    if (more) {
      pa[0] = *(const h8*)(A + arow0 + kt + 32 + tkc);
      pa[1] = *(const h8*)(A + arow1 + kt + 32 + tkc);
      pb[0] = *(const h8*)(Bt + brow0 + kt + 32 + tkc);
      pb[1] = *(const h8*)(Bt + brow1 + kt + 32 + tkc);
    }
    h8 af[2], bf[8];
#pragma unroll
    for (int i = 0; i < 2; i++)
      af[i] = *(h8*)&As[curo + (wave * 32 + i * 16 + lr) * 40 + quad * 8];
#pragma unroll
    for (int j = 0; j < 8; j++)
      bf[j] = *(h8*)&Bs[curo + (j * 16 + lr) * 40 + quad * 8];
#pragma unroll
    for (int i = 0; i < 2; i++)
#pragma unroll
      for (int j = 0; j < 8; j++)
        acc[i][j] = __builtin_amdgcn_mfma_f32_16x16x32_f16(af[i], bf[j], acc[i][j], 0, 0, 0);
    if (more) {
      const int nxto = (cur ^ 1) * 5120;
      *(h8*)&As[nxto + trow * 40 + tkc] = pa[0];
      *(h8*)&As[nxto + (trow + 64) * 40 + tkc] = pa[1];
      *(h8*)&Bs[nxto + trow * 40 + tkc] = pb[0];
      *(h8*)&Bs[nxto + (trow + 64) * 40 + tkc] = pb[1];
      __syncthreads();
    }
  }

  // per-thread row weights (8 rows), loaded once
  float2 wrow[2][4];
#pragma unroll
  for (int i = 0; i < 2; i++)
#pragma unroll
    for (int r = 0; r < 4; r++) {
      int gr = m0 + wave * 32 + i * 16 + quad * 4 + r;
      wrow[i][r] = (gr < M) ? dd[gr] : make_float2(0.f, 0.f);
    }

#pragma unroll
  for (int jm = 0; jm < 4; jm++) {
    int c = jm * 16 + lr;                 // class col 0..63
    float bm = bm1[c], bv = bv1[c];
#pragma unroll
    for (int i = 0; i < 2; i++) {
#pragma unroll
      for (int r = 0; r < 4; r++) {
        int gr = m0 + wave * 32 + i * 16 + quad * 4 + r;
        if (gr < M) {
          float zm = acc[i][jm][r] + bm;
          float zv = acc[i][4 + jm][r] + bv;
          float m = elu_f(zm);
          float v = fmaxf(zv, 0.f) + 1e-6f;
          float a = __expf(-v);
          h2 pk;
          pk.x = (_Float16)(m * a * wrow[i][r].x);       // dis_r * mean*attn
          pk.y = (_Float16)(v * a * a * wrow[i][r].y);   // di_r * var*attn^2
          Mcat[(size_t)gr * 64 + c] = __builtin_bit_cast(uint32, pk);
        }
      }
    }
  }
}

// ---------------- fused dual SpMM + reparam + log_softmax ----------------
// Mcat rows pre-scaled by dst weights -> pure gather+sum. 8 gathers in flight.
__global__ __launch_bounds__(256) void spmm_final_k(
    const uint32* __restrict__ Mcat, const float2* __restrict__ dd,
    const int* __restrict__ row_start, const int* __restrict__ cnt,
    const int* __restrict__ csr, const float* __restrict__ sample,
    float* __restrict__ out, int n) {
  int wid = threadIdx.x >> 6, lane = threadIdx.x & 63;
  int r = blockIdx.x * 4 + wid;
  if (r >= n) return;
  float2 wr = dd[r];
  h2 self = __builtin_bit_cast(h2, Mcat[(size_t)r * 64 + lane]);
  float Sm = (float)self.x;           // already dis_r-scaled
  float Sv = (float)self.y;           // already di_r-scaled
  int start = __builtin_amdgcn_readfirstlane(row_start[r]);
  int c = __builtin_amdgcn_readfirstlane(cnt[r]);
  int j = 0;
  for (; j + 8 <= c; j += 8) {
    int4 da = *(const int4*)(csr + start + j);
    int4 db = *(const int4*)(csr + start + j + 4);
    h2 p0 = __builtin_bit_cast(h2, Mcat[(size_t)da.x * 64 + lane]);
    h2 p1 = __builtin_bit_cast(h2, Mcat[(size_t)da.y * 64 + lane]);
    h2 p2 = __builtin_bit_cast(h2, Mcat[(size_t)da.z * 64 + lane]);
    h2 p3 = __builtin_bit_cast(h2, Mcat[(size_t)da.w * 64 + lane]);
    h2 p4 = __builtin_bit_cast(h2, Mcat[(size_t)db.x * 64 + lane]);
    h2 p5 = __builtin_bit_cast(h2, Mcat[(size_t)db.y * 64 + lane]);
    h2 p6 = __builtin_bit_cast(h2, Mcat[(size_t)db.z * 64 + lane]);
    h2 p7 = __builtin_bit_cast(h2, Mcat[(size_t)db.w * 64 + lane]);
    Sm += (float)p0.x + (float)p1.x + (float)p2.x + (float)p3.x;
    Sv += (float)p0.y + (float)p1.y + (float)p2.y + (float)p3.y;
    Sm += (float)p4.x + (float)p5.x + (float)p6.x + (float)p7.x;
    Sv += (float)p4.y + (float)p5.y + (float)p6.y + (float)p7.y;
  }
  if (j + 4 <= c) {
    int4 d4 = *(const int4*)(csr + start + j);
    h2 p0 = __builtin_bit_cast(h2, Mcat[(size_t)d4.x * 64 + lane]);
    h2 p1 = __builtin_bit_cast(h2, Mcat[(size_t)d4.y * 64 + lane]);
    h2 p2 = __builtin_bit_cast(h2, Mcat[(size_t)d4.z * 64 + lane]);
    h2 p3 = __builtin_bit_cast(h2, Mcat[(size_t)d4.w * 64 + lane]);
    Sm += (float)p0.x + (float)p1.x + (float)p2.x + (float)p3.x;
    Sv += (float)p0.y + (float)p1.y + (float)p2.y + (float)p3.y;
    j += 4;
  }
  for (; j < c; j++) {
    int d = csr[start + j];
    h2 p = __builtin_bit_cast(h2, Mcat[(size_t)d * 64 + lane]);
    Sm += (float)p.x;
    Sv += (float)p.y;
  }
  float mean = wr.x * Sm;
  float var = wr.y * Sv;
  float o = mean + sample[(size_t)r * 64 + lane] * sqrtf(var);
  float mx = o;
#pragma unroll
  for (int off = 32; off; off >>= 1) mx = fmaxf(mx, __shfl_xor(mx, off, 64));
  float ex = __expf(o - mx);
  float s = ex;
#pragma unroll
  for (int off = 32; off; off >>= 1) s += __shfl_xor(s, off, 64);
  out[(size_t)r * 64 + lane] = o - mx - logf(s);
}

// ---------------- launch ----------------
extern "C" void kernel_launch(void* const* d_in, const int* in_sizes, int n_in,
                              void* d_out, int out_size, void* d_ws, size_t ws_size,
                              hipStream_t stream) {
  (void)n_in; (void)out_size; (void)ws_size;
  const float* x    = (const float*)d_in[0];
  const float* Wm0  = (const float*)d_in[1];
  const float* bm0  = (const float*)d_in[2];
  const float* Wv0  = (const float*)d_in[3];
  const float* bv0  = (const float*)d_in[4];
  const float* Wm1  = (const float*)d_in[5];
  const float* bm1  = (const float*)d_in[6];
  const float* Wv1  = (const float*)d_in[7];
  const float* bv1  = (const float*)d_in[8];
  const float* sample = (const float*)d_in[9];
  const int* esrc   = (const int*)d_in[10];
  const int* edst   = (const int*)d_in[11];
  float* out = (float*)d_out;

  const int N = in_sizes[0] / 512;
  const int E = in_sizes[10];

  uint8_t* p = (uint8_t*)d_ws;
  size_t off = 0;
  auto alloc = [&](size_t bytes) -> void* {
    void* r = p + off;
    off += (bytes + 255) & ~(size_t)255;
    return r;
  };
  _Float16* W1t  = (_Float16*)alloc((size_t)512 * 512 * 2);
  _Float16* W2t  = (_Float16*)alloc((size_t)128 * 512 * 2);
  _Float16* Hcat = (_Float16*)alloc((size_t)N * 512 * 2);
  uint32*   Mcat = (uint32*)alloc((size_t)N * 64 * 4);
  int*   cnt    = (int*)alloc((size_t)N * 4);
  float2* dd    = (float2*)alloc((size_t)N * 8);
  int*   rs     = (int*)alloc((size_t)N * 4);
  int*   cur    = (int*)alloc((size_t)N * 4);
  int*   bsum   = (int*)alloc(2048);
  int*   boff   = (int*)alloc(2048);
  int*   csr    = (int*)alloc((size_t)(E + 4 * N) * 4);  // padded rows

  const int nbN = (N + 255) / 256;
  const int nbE = (E + 255) / 256;

  prep_w_k<<<(512 * 512 + 255) / 256, 256, 0, stream>>>(Wm0, Wv0, Wm1, Wv1, W1t, W2t);
  zero_k<<<nbN, 256, 0, stream>>>(cnt, N);
  countA_k<<<nbE, 256, 0, stream>>>(esrc, E, cnt);
  scan1_k<<<nbN, 256, 0, stream>>>(cnt, rs, bsum, dd, N);
  scan2_k<<<1, 512, 0, stream>>>(bsum, boff, nbN);
  scan3_k<<<nbN, 256, 0, stream>>>(rs, boff, cur, N);
  scatterA_k<<<nbE, 256, 0, stream>>>(esrc, edst, E, cur, csr);

  const int mtiles = (N + 127) / 128;
  const int sgroups = (mtiles + 7) / 8;
  gemm1f_k<<<sgroups * 32, 256, 0, stream>>>(x, W1t, bm0, bv0, Hcat, N, mtiles);
  gemm2_k<<<mtiles, 256, 0, stream>>>(Hcat, W2t, bm1, bv1, dd, Mcat, N, 512);
  spmm_final_k<<<(N + 3) / 4, 256, 0, stream>>>(Mcat, dd, rs, cnt, csr, sample, out, N);
}

// Round 7
// 698.462 us; speedup vs baseline: 1.3883x; 1.3883x over previous
//
#include <hip/hip_runtime.h>
#include <cstdint>
#include <cstddef>

// RobustGCN forward on MI355X — best-known composite (r7).
//   1. graph prep — deterministic bucket sort (bucket = src>>7), no global atomics:
//      hist -> btotal/bscan/boff -> bscatter(int2 pairs) -> countN(+deg weights)
//      -> padded scans -> partC (per-bucket CSR scatter via LDS cursors).
//      (r6 lesson: global-atomic scatter = 280us from 15x write-amplification;
//       bucket-dense CSR writes are the whole point.)
//   2. GEMM1 (r2-proven gemm1f, 177us): BM=BN=128, BK=32, 4 waves, dbuf 48KB LDS,
//      A f32 + B f16 via global_load_lds width-16 (linear dest, inv-swizzled src),
//      cvt at frag build, 3 blocks/CU. (r1: BN=512/1blk = latency-bound. r3:
//      3-buf/counted-vmcnt lost occupancy. r4: cvtx pass costs > saves. r5:
//      reg-staged A + ds_write = 226us.)
//   3. GEMM2 (f16 MFMA, reg-dbuf, block-diag W) + fused attention epilogue ->
//      Mcat[r][c] = pack_h2(dis_r*m*exp(-v), di_r*v*exp(-2v))  (deg weights FOLDED)
//   4. fused dual SpMM (CSR, wave/node, lane/class, 8 gathers in flight) —
//      no dd gather in hot loop + sample*sqrt(var) + log_softmax

typedef _Float16 h8 __attribute__((ext_vector_type(8)));
typedef _Float16 h2 __attribute__((ext_vector_type(2)));
typedef float f32x4 __attribute__((ext_vector_type(4)));
typedef unsigned int uint32;

#define BSHIFT 7              // 128 nodes per bucket
#define NCHUNK 256            // edge chunks (blocks) in sort passes

static __device__ __forceinline__ float elu_f(float z) {
  return z > 0.f ? z : expm1f(z);
}

// async global->LDS, 16B per lane. Dest must be wave-linear (base + lane*16).
static __device__ __forceinline__ void gload16(const void* g, void* l) {
  __builtin_amdgcn_global_load_lds(
      (__attribute__((address_space(1))) void*)g,
      (__attribute__((address_space(3))) void*)l, 16, 0, 0);
}

// ---------------- bucket sort ----------------
__global__ __launch_bounds__(256) void hist_k(const int* __restrict__ esrc, int E,
                                              int chunk, int* __restrict__ h, int NB) {
  __shared__ int sh[1024];
  int t = threadIdx.x;
  for (int i = t; i < NB; i += 256) sh[i] = 0;
  __syncthreads();
  int e0 = blockIdx.x * chunk;
  int e1 = min(e0 + chunk, E);
  for (int e = e0 + t; e < e1; e += 256) atomicAdd(&sh[esrc[e] >> BSHIFT], 1);
  __syncthreads();
  for (int i = t; i < NB; i += 256) h[blockIdx.x * NB + i] = sh[i];
}

__global__ __launch_bounds__(256) void btotal_k(const int* __restrict__ h,
                                                int* __restrict__ tot, int NB) {
  int b = blockIdx.x, t = threadIdx.x;
  int v = h[t * NB + b];
#pragma unroll
  for (int off = 32; off; off >>= 1) v += __shfl_xor(v, off, 64);
  __shared__ int sw[4];
  if ((t & 63) == 0) sw[t >> 6] = v;
  __syncthreads();
  if (t == 0) tot[b] = sw[0] + sw[1] + sw[2] + sw[3];
}

__global__ __launch_bounds__(1024) void bscan_k(const int* __restrict__ tot,
                                                int* __restrict__ base, int NB) {
  __shared__ int sh[1024];
  int t = threadIdx.x;
  int v = (t < NB) ? tot[t] : 0;
  sh[t] = v;
  __syncthreads();
  for (int off = 1; off < 1024; off <<= 1) {
    int add = (t >= off) ? sh[t - off] : 0;
    __syncthreads();
    sh[t] += add;
    __syncthreads();
  }
  if (t < NB) base[t] = sh[t] - v;
  if (t == 1023) base[NB] = sh[1023];
}

__global__ __launch_bounds__(256) void boff_k(int* __restrict__ h,
                                              const int* __restrict__ base, int NB) {
  __shared__ int sh[256];
  int b = blockIdx.x, t = threadIdx.x;
  int v = h[t * NB + b];
  sh[t] = v;
  __syncthreads();
  for (int off = 1; off < 256; off <<= 1) {
    int add = (t >= off) ? sh[t - off] : 0;
    __syncthreads();
    sh[t] += add;
    __syncthreads();
  }
  h[t * NB + b] = base[b] + sh[t] - v;
}

__global__ __launch_bounds__(256) void bscatter_k(
    const int* __restrict__ esrc, const int* __restrict__ edst, int E, int chunk,
    const int* __restrict__ h, int2* __restrict__ pairs, int NB) {
  __shared__ int lcur[1024];
  int t = threadIdx.x;
  for (int i = t; i < NB; i += 256) lcur[i] = h[blockIdx.x * NB + i];
  __syncthreads();
  int e0 = blockIdx.x * chunk;
  int e1 = min(e0 + chunk, E);
  for (int e = e0 + t; e < e1; e += 256) {
    int s = esrc[e], d = edst[e];
    int pos = atomicAdd(&lcur[s >> BSHIFT], 1);
    pairs[pos] = make_int2(s, d);
  }
}

// per-node degree (bucket sort makes per-bucket counts complete) + degree weights
__global__ __launch_bounds__(256) void countN_k(
    const int2* __restrict__ pairs, const int* __restrict__ base,
    int* __restrict__ cnt, float2* __restrict__ dd, int n) {
  __shared__ int c128[128];
  int b = blockIdx.x, t = threadIdx.x;
  if (t < 128) c128[t] = 0;
  __syncthreads();
  int lo = base[b], hi = base[b + 1];
  for (int i = lo + t; i < hi; i += 256) atomicAdd(&c128[pairs[i].x & 127], 1);
  __syncthreads();
  if (t < 128) {
    int node = b * 128 + t;
    if (node < n) {
      int c = c128[t];
      cnt[node] = c;
      float d = (float)(c + 1);  // +1 self loop
      dd[node] = make_float2(rsqrtf(d), 1.f / d);
    }
  }
}

__global__ __launch_bounds__(256) void partC_k(
    const int2* __restrict__ pairs, const int* __restrict__ base,
    const int* __restrict__ rs, int* __restrict__ csr, int n) {
  __shared__ int lcur[128];
  int b = blockIdx.x, t = threadIdx.x;
  if (t < 128) {
    int node = b * 128 + t;
    lcur[t] = (node < n) ? rs[node] : 0;
  }
  __syncthreads();
  int lo = base[b], hi = base[b + 1];
  for (int i = lo + t; i < hi; i += 256) {
    int2 pr = pairs[i];
    int pos = atomicAdd(&lcur[pr.x & 127], 1);
    csr[pos] = pr.y;
  }
}

// ---------------- padded row-start scan ----------------
// exclusive scan of PADDED counts ((cnt+3)&~3) so every CSR row start is 16B-aligned
__global__ void scan1_k(const int* __restrict__ cnt, int* __restrict__ excl,
                        int* __restrict__ bsum, int n) {
  __shared__ int sh[256];
  int t = threadIdx.x, idx = blockIdx.x * 256 + t;
  int v = (idx < n) ? ((cnt[idx] + 3) & ~3) : 0;
  sh[t] = v;
  __syncthreads();
  for (int off = 1; off < 256; off <<= 1) {
    int add = (t >= off) ? sh[t - off] : 0;
    __syncthreads();
    sh[t] += add;
    __syncthreads();
  }
  if (idx < n) excl[idx] = sh[t] - v;
  if (t == 255) bsum[blockIdx.x] = sh[255];
}

__global__ void scan2_k(const int* __restrict__ bsum, int* __restrict__ boff, int nb) {
  __shared__ int sh[512];
  int t = threadIdx.x;
  int v = (t < nb) ? bsum[t] : 0;
  sh[t] = v;
  __syncthreads();
  for (int off = 1; off < 512; off <<= 1) {
    int add = (t >= off) ? sh[t - off] : 0;
    __syncthreads();
    sh[t] += add;
    __syncthreads();
  }
  if (t < nb) boff[t] = sh[t] - v;
}

__global__ void scan3_k(int* __restrict__ excl, const int* __restrict__ boff, int n) {
  int idx = blockIdx.x * 256 + threadIdx.x;
  if (idx < n) excl[idx] += boff[blockIdx.x];
}

// ---------------- weight prep: transpose + f16 + fuse ----------------
__global__ void prep_w_k(const float* __restrict__ Wm0, const float* __restrict__ Wv0,
                         const float* __restrict__ Wm1, const float* __restrict__ Wv1,
                         _Float16* __restrict__ W1t, _Float16* __restrict__ W2t) {
  int idx = blockIdx.x * 256 + threadIdx.x;
  if (idx < 512 * 512) {
    int n = idx >> 9, k = idx & 511;
    float v = (n < 256) ? Wm0[k * 256 + n] : Wv0[k * 256 + (n - 256)];
    W1t[idx] = (_Float16)v;
  }
  if (idx < 128 * 512) {
    int n = idx >> 9, k = idx & 511;
    float v = 0.f;
    if (n < 64) { if (k < 256) v = Wm1[k * 64 + n]; }
    else        { if (k >= 256) v = Wv1[(k - 256) * 64 + (n - 64)]; }
    W2t[idx] = (_Float16)v;
  }
}

// ---------------- GEMM1 (r2-proven): Hcat = act(x @ W1t^T + b) ----------------
// BM=128, BN=128, BK=32, K=512 (16 iters). 4 waves (2m x 2n), acc 4x4 frags.
// LDS 48KB: Af32[2][128][32] @ 0/16384 (16B-slot swizzle ^row&7),
//           Bf16[2][128][32] @ 32768/40960 (16B-slot swizzle ^(row>>1)&3).
// global_load_lds width-16, linear LDS dest, inverse-swizzled global source.
// 3 blocks/CU -> cross-block overlap hides per-iter vmcnt(0)+barrier drain.
__global__ __launch_bounds__(256) void gemm1f_k(
    const float* __restrict__ A, const _Float16* __restrict__ Bt,
    const float* __restrict__ b0, const float* __restrict__ b1,
    _Float16* __restrict__ out, int M, int mtiles) {
  __shared__ __align__(16) unsigned char ldsb[49152];

  const int sg = blockIdx.x >> 5, loc = blockIdx.x & 31;
  const int nt = loc >> 3, mtl = loc & 7;
  const int mt = sg * 8 + mtl;
  if (mt >= mtiles) return;
  const int m0 = mt * 128, n0 = nt * 128;
  const int t = threadIdx.x;
  const int lane = t & 63;
  const int wave = t >> 6;
  const int wm = wave >> 1, wn = wave & 1;
  const int lr = lane & 15, quad = lane >> 4;

  const int ra = t >> 3;
  const int asw = ((t & 7) ^ (ra & 7)) << 2;
  const int rb = t >> 2;
  const int bsw = ((t & 3) ^ ((t >> 3) & 3)) << 3;

  f32x4 acc[4][4] = {};

  auto stage = [&](int b, int kt) {
#pragma unroll
    for (int i = 0; i < 4; i++) {
      const float* src = A + (size_t)min(m0 + i * 32 + ra, M - 1) * 512 + kt + asw;
      gload16(src, ldsb + b * 16384 + i * 4096 + t * 16);
    }
#pragma unroll
    for (int i = 0; i < 2; i++) {
      const _Float16* src = Bt + (size_t)(n0 + i * 64 + rb) * 512 + kt + bsw;
      gload16(src, ldsb + 32768 + b * 8192 + i * 4096 + t * 16);
    }
  };

  stage(0, 0);
  __syncthreads();

  int cur = 0;
  const int zA = lr & 7;
  const int zB = (lr >> 1) & 3;
  for (int kt = 0; kt < 512; kt += 32) {
    if (kt + 32 < 512) stage(cur ^ 1, kt + 32);
    const unsigned char* Ab = ldsb + cur * 16384;
    const unsigned char* Bb = ldsb + 32768 + cur * 8192;
    h8 bf[4];
#pragma unroll
    for (int j = 0; j < 4; j++) {
      int row = wn * 64 + j * 16 + lr;
      bf[j] = *(const h8*)(Bb + row * 64 + ((quad ^ zB) << 4));
    }
    h8 af[4];
#pragma unroll
    for (int i = 0; i < 4; i++) {
      int R = wm * 64 + i * 16 + lr;
      const float4 a0 = *(const float4*)(Ab + R * 128 + (((2 * quad) ^ zA) << 4));
      const float4 a1 = *(const float4*)(Ab + R * 128 + (((2 * quad + 1) ^ zA) << 4));
      af[i] = h8{(_Float16)a0.x, (_Float16)a0.y, (_Float16)a0.z, (_Float16)a0.w,
                 (_Float16)a1.x, (_Float16)a1.y, (_Float16)a1.z, (_Float16)a1.w};
    }
#pragma unroll
    for (int i = 0; i < 4; i++)
#pragma unroll
      for (int j = 0; j < 4; j++)
        acc[i][j] = __builtin_amdgcn_mfma_f32_16x16x32_f16(af[i], bf[j], acc[i][j], 0, 0, 0);
    __syncthreads();
    cur ^= 1;
  }

  // epilogue: bias+act in regs -> f16 LDS tile (stride 136) -> 16B coalesced stores
  _Float16* lt = (_Float16*)ldsb;
#pragma unroll
  for (int j = 0; j < 4; j++) {
    int gc = n0 + wn * 64 + j * 16 + lr;
    float bj = (gc < 256) ? b0[gc] : b1[gc - 256];
#pragma unroll
    for (int i = 0; i < 4; i++) {
#pragma unroll
      for (int r = 0; r < 4; r++) {
        float z = acc[i][j][r] + bj;
        float v = (gc < 256) ? elu_f(z) : fmaxf(z, 0.f);
        lt[(wm * 64 + i * 16 + quad * 4 + r) * 136 + wn * 64 + j * 16 + lr] = (_Float16)v;
      }
    }
  }
  __syncthreads();
  {
    const int row = t >> 1, col0 = (t & 1) * 64;
    const int gr = m0 + row;
    if (gr < M) {
      _Float16* dst = out + (size_t)gr * 512 + n0 + col0;
#pragma unroll
      for (int k = 0; k < 8; k++)
        *(h8*)(dst + k * 8) = *(h8*)&lt[row * 136 + col0 + k * 8];
    }
  }
}

// ---------------- GEMM2 + fused attention (reg-dbuf) ----------------
// BM=128, N=128 (cols 0..63 mean, 64..127 var). 4 waves, wave = 32 rows x 8 j-tiles.
// Epilogue folds the dst-side degree weights into Mcat:
//   Mcat[r][c] = pack_h2(dis_r * m*exp(-v), di_r * v*exp(-2v))
// so the SpMM gather needs NO dd[dst] lookup (w0=dis_s*dis_d, w1=di_s*di_d).
__global__ __launch_bounds__(256) void gemm2_k(
    const _Float16* __restrict__ A, const _Float16* __restrict__ Bt,
    const float* __restrict__ bm1, const float* __restrict__ bv1,
    const float2* __restrict__ dd, uint32* __restrict__ Mcat, int M, int K) {
  __shared__ _Float16 lds[20480];
  _Float16* As = lds;
  _Float16* Bs = lds + 10240;
  const int m0 = blockIdx.x * 128;
  const int t = threadIdx.x;
  const int lane = t & 63;
  const int wave = t >> 6;
  const int lr = lane & 15, quad = lane >> 4;
  const int trow = t >> 2;
  const int tkc = (t & 3) * 8;

  const size_t arow0 = (size_t)min(m0 + trow, M - 1) * K;
  const size_t arow1 = (size_t)min(m0 + trow + 64, M - 1) * K;
  const size_t brow0 = (size_t)trow * K;
  const size_t brow1 = (size_t)(trow + 64) * K;

  f32x4 acc[2][8] = {};
  h8 pa[2], pb[2];

  pa[0] = *(const h8*)(A + arow0 + tkc);
  pa[1] = *(const h8*)(A + arow1 + tkc);
  pb[0] = *(const h8*)(Bt + brow0 + tkc);
  pb[1] = *(const h8*)(Bt + brow1 + tkc);
  *(h8*)&As[trow * 40 + tkc] = pa[0];
  *(h8*)&As[(trow + 64) * 40 + tkc] = pa[1];
  *(h8*)&Bs[trow * 40 + tkc] = pb[0];
  *(h8*)&Bs[(trow + 64) * 40 + tkc] = pb[1];
  __syncthreads();

  for (int kt = 0; kt < K; kt += 32) {
    const int cur = (kt >> 5) & 1;
    const int curo = cur * 5120;
    const bool more = (kt + 32) < K;
    if (more) {
      pa[0] = *(const h8*)(A + arow0 + kt + 32 + tkc);
      pa[1] = *(const h8*)(A + arow1 + kt + 32 + tkc);
      pb[0] = *(const h8*)(Bt + brow0 + kt + 32 + tkc);
      pb[1] = *(const h8*)(Bt + brow1 + kt + 32 + tkc);
    }
    h8 af[2], bf[8];
#pragma unroll
    for (int i = 0; i < 2; i++)
      af[i] = *(h8*)&As[curo + (wave * 32 + i * 16 + lr) * 40 + quad * 8];
#pragma unroll
    for (int j = 0; j < 8; j++)
      bf[j] = *(h8*)&Bs[curo + (j * 16 + lr) * 40 + quad * 8];
#pragma unroll
    for (int i = 0; i < 2; i++)
#pragma unroll
      for (int j = 0; j < 8; j++)
        acc[i][j] = __builtin_amdgcn_mfma_f32_16x16x32_f16(af[i], bf[j], acc[i][j], 0, 0, 0);
    if (more) {
      const int nxto = (cur ^ 1) * 5120;
      *(h8*)&As[nxto + trow * 40 + tkc] = pa[0];
      *(h8*)&As[nxto + (trow + 64) * 40 + tkc] = pa[1];
      *(h8*)&Bs[nxto + trow * 40 + tkc] = pb[0];
      *(h8*)&Bs[nxto + (trow + 64) * 40 + tkc] = pb[1];
      __syncthreads();
    }
  }

  // per-thread row weights (8 rows), loaded once
  float2 wrow[2][4];
#pragma unroll
  for (int i = 0; i < 2; i++)
#pragma unroll
    for (int r = 0; r < 4; r++) {
      int gr = m0 + wave * 32 + i * 16 + quad * 4 + r;
      wrow[i][r] = (gr < M) ? dd[gr] : make_float2(0.f, 0.f);
    }

#pragma unroll
  for (int jm = 0; jm < 4; jm++) {
    int c = jm * 16 + lr;                 // class col 0..63
    float bm = bm1[c], bv = bv1[c];
#pragma unroll
    for (int i = 0; i < 2; i++) {
#pragma unroll
      for (int r = 0; r < 4; r++) {
        int gr = m0 + wave * 32 + i * 16 + quad * 4 + r;
        if (gr < M) {
          float zm = acc[i][jm][r] + bm;
          float zv = acc[i][4 + jm][r] + bv;
          float m = elu_f(zm);
          float v = fmaxf(zv, 0.f) + 1e-6f;
          float a = __expf(-v);
          h2 pk;
          pk.x = (_Float16)(m * a * wrow[i][r].x);       // dis_r * mean*attn
          pk.y = (_Float16)(v * a * a * wrow[i][r].y);   // di_r * var*attn^2
          Mcat[(size_t)gr * 64 + c] = __builtin_bit_cast(uint32, pk);
        }
      }
    }
  }
}

// ---------------- fused dual SpMM + reparam + log_softmax ----------------
// Mcat rows pre-scaled by dst weights -> pure gather+sum. 8 gathers in flight.
__global__ __launch_bounds__(256) void spmm_final_k(
    const uint32* __restrict__ Mcat, const float2* __restrict__ dd,
    const int* __restrict__ row_start, const int* __restrict__ cnt,
    const int* __restrict__ csr, const float* __restrict__ sample,
    float* __restrict__ out, int n) {
  int wid = threadIdx.x >> 6, lane = threadIdx.x & 63;
  int r = blockIdx.x * 4 + wid;
  if (r >= n) return;
  float2 wr = dd[r];
  h2 self = __builtin_bit_cast(h2, Mcat[(size_t)r * 64 + lane]);
  float Sm = (float)self.x;           // already dis_r-scaled
  float Sv = (float)self.y;           // already di_r-scaled
  int start = __builtin_amdgcn_readfirstlane(row_start[r]);
  int c = __builtin_amdgcn_readfirstlane(cnt[r]);
  int j = 0;
  for (; j + 8 <= c; j += 8) {
    int4 da = *(const int4*)(csr + start + j);
    int4 db = *(const int4*)(csr + start + j + 4);
    h2 p0 = __builtin_bit_cast(h2, Mcat[(size_t)da.x * 64 + lane]);
    h2 p1 = __builtin_bit_cast(h2, Mcat[(size_t)da.y * 64 + lane]);
    h2 p2 = __builtin_bit_cast(h2, Mcat[(size_t)da.z * 64 + lane]);
    h2 p3 = __builtin_bit_cast(h2, Mcat[(size_t)da.w * 64 + lane]);
    h2 p4 = __builtin_bit_cast(h2, Mcat[(size_t)db.x * 64 + lane]);
    h2 p5 = __builtin_bit_cast(h2, Mcat[(size_t)db.y * 64 + lane]);
    h2 p6 = __builtin_bit_cast(h2, Mcat[(size_t)db.z * 64 + lane]);
    h2 p7 = __builtin_bit_cast(h2, Mcat[(size_t)db.w * 64 + lane]);
    Sm += (float)p0.x + (float)p1.x + (float)p2.x + (float)p3.x;
    Sv += (float)p0.y + (float)p1.y + (float)p2.y + (float)p3.y;
    Sm += (float)p4.x + (float)p5.x + (float)p6.x + (float)p7.x;
    Sv += (float)p4.y + (float)p5.y + (float)p6.y + (float)p7.y;
  }
  if (j + 4 <= c) {
    int4 d4 = *(const int4*)(csr + start + j);
    h2 p0 = __builtin_bit_cast(h2, Mcat[(size_t)d4.x * 64 + lane]);
    h2 p1 = __builtin_bit_cast(h2, Mcat[(size_t)d4.y * 64 + lane]);
    h2 p2 = __builtin_bit_cast(h2, Mcat[(size_t)d4.z * 64 + lane]);
    h2 p3 = __builtin_bit_cast(h2, Mcat[(size_t)d4.w * 64 + lane]);
    Sm += (float)p0.x + (float)p1.x + (float)p2.x + (float)p3.x;
    Sv += (float)p0.y + (float)p1.y + (float)p2.y + (float)p3.y;
    j += 4;
  }
  for (; j < c; j++) {
    int d = csr[start + j];
    h2 p = __builtin_bit_cast(h2, Mcat[(size_t)d * 64 + lane]);
    Sm += (float)p.x;
    Sv += (float)p.y;
  }
  float mean = wr.x * Sm;
  float var = wr.y * Sv;
  float o = mean + sample[(size_t)r * 64 + lane] * sqrtf(var);
  float mx = o;
#pragma unroll
  for (int off = 32; off; off >>= 1) mx = fmaxf(mx, __shfl_xor(mx, off, 64));
  float ex = __expf(o - mx);
  float s = ex;
#pragma unroll
  for (int off = 32; off; off >>= 1) s += __shfl_xor(s, off, 64);
  out[(size_t)r * 64 + lane] = o - mx - logf(s);
}

// ---------------- launch ----------------
extern "C" void kernel_launch(void* const* d_in, const int* in_sizes, int n_in,
                              void* d_out, int out_size, void* d_ws, size_t ws_size,
                              hipStream_t stream) {
  (void)n_in; (void)out_size; (void)ws_size;
  const float* x    = (const float*)d_in[0];
  const float* Wm0  = (const float*)d_in[1];
  const float* bm0  = (const float*)d_in[2];
  const float* Wv0  = (const float*)d_in[3];
  const float* bv0  = (const float*)d_in[4];
  const float* Wm1  = (const float*)d_in[5];
  const float* bm1  = (const float*)d_in[6];
  const float* Wv1  = (const float*)d_in[7];
  const float* bv1  = (const float*)d_in[8];
  const float* sample = (const float*)d_in[9];
  const int* esrc   = (const int*)d_in[10];
  const int* edst   = (const int*)d_in[11];
  float* out = (float*)d_out;

  const int N = in_sizes[0] / 512;
  const int E = in_sizes[10];
  const int NB = (N + 127) >> BSHIFT;          // 128-node buckets
  const int chunk = (E + NCHUNK - 1) / NCHUNK;

  uint8_t* p = (uint8_t*)d_ws;
  size_t off = 0;
  auto alloc = [&](size_t bytes) -> void* {
    void* r = p + off;
    off += (bytes + 255) & ~(size_t)255;
    return r;
  };
  _Float16* W1t  = (_Float16*)alloc((size_t)512 * 512 * 2);
  _Float16* W2t  = (_Float16*)alloc((size_t)128 * 512 * 2);
  _Float16* Hcat = (_Float16*)alloc((size_t)N * 512 * 2);
  uint32*   Mcat = (uint32*)alloc((size_t)N * 64 * 4);
  int*   cnt    = (int*)alloc((size_t)N * 4);
  float2* dd    = (float2*)alloc((size_t)N * 8);
  int*   rs     = (int*)alloc((size_t)N * 4);
  int*   h      = (int*)alloc((size_t)NCHUNK * NB * 4);
  int*   tot    = (int*)alloc((size_t)(NB + 1) * 4);
  int*   base   = (int*)alloc((size_t)(NB + 1) * 4);
  int*   bsum   = (int*)alloc(2048);
  int*   boff   = (int*)alloc(2048);
  int*   csr    = (int*)alloc((size_t)(E + 4 * N) * 4);  // padded rows
  // bucket-sorted pairs only live before gemm1 writes Hcat:
  int2* pairs = (int2*)Hcat;     // E*8 = 25.6MB <= Hcat's 102.4MB

  const int nbN = (N + 255) / 256;

  prep_w_k<<<(512 * 512 + 255) / 256, 256, 0, stream>>>(Wm0, Wv0, Wm1, Wv1, W1t, W2t);
  hist_k<<<NCHUNK, 256, 0, stream>>>(esrc, E, chunk, h, NB);
  btotal_k<<<NB, 256, 0, stream>>>(h, tot, NB);
  bscan_k<<<1, 1024, 0, stream>>>(tot, base, NB);
  boff_k<<<NB, 256, 0, stream>>>(h, base, NB);
  bscatter_k<<<NCHUNK, 256, 0, stream>>>(esrc, edst, E, chunk, h, pairs, NB);
  countN_k<<<NB, 256, 0, stream>>>(pairs, base, cnt, dd, N);
  scan1_k<<<nbN, 256, 0, stream>>>(cnt, rs, bsum, N);
  scan2_k<<<1, 512, 0, stream>>>(bsum, boff, nbN);
  scan3_k<<<nbN, 256, 0, stream>>>(rs, boff, N);
  partC_k<<<NB, 256, 0, stream>>>(pairs, base, rs, csr, N);

  const int mtiles = (N + 127) / 128;
  const int sgroups = (mtiles + 7) / 8;
  gemm1f_k<<<sgroups * 32, 256, 0, stream>>>(x, W1t, bm0, bv0, Hcat, N, mtiles);
  gemm2_k<<<mtiles, 256, 0, stream>>>(Hcat, W2t, bm1, bv1, dd, Mcat, N, 512);
  spmm_final_k<<<(N + 3) / 4, 256, 0, stream>>>(Mcat, dd, rs, cnt, csr, sample, out, N);
}